// Round 4
// baseline (157.440 us; speedup 1.0000x reference)
//
#include <hip/hip_runtime.h>
#include <hip/hip_bf16.h>
#include <stdint.h>

typedef __attribute__((ext_vector_type(8))) short s16x8;
typedef __attribute__((ext_vector_type(4))) float f32x4;

#define T_   2048
#define NH   16
#define HD   64
#define DIN  1024
#define SCALE_LOG2 0.18033688011112042f  // (1/8)*log2(e)

#define MFMA32(a, b, c) __builtin_amdgcn_mfma_f32_16x16x32_bf16(a, b, c, 0, 0, 0)

// RTNE fp32 -> bf16
__device__ __forceinline__ unsigned short f2bf(float f) {
  union { float f; uint32_t u; } c; c.f = f;
  uint32_t u = c.u;
  return (unsigned short)((u + 0x7FFFu + ((u >> 16) & 1u)) >> 16);
}

__device__ __forceinline__ uint32_t pk_bf16(float a, float b) {
  __hip_bfloat162 h = __float22bfloat162_rn(make_float2(a, b));
  return *reinterpret_cast<uint32_t*>(&h);
}

// async global->LDS, 16B per lane; dest = wave-uniform base + lane*16
#define GLL(gp, lp) __builtin_amdgcn_global_load_lds( \
    (__attribute__((address_space(1))) void*)(gp),    \
    (__attribute__((address_space(3))) void*)(lp), 16, 0, 0)

// ---------------- kernel 1: fp32 -> bf16 conversion ----------------
__global__ __launch_bounds__(256) void cvt_kernel(
    const float* __restrict__ x,  const float* __restrict__ wq,
    const float* __restrict__ wk, const float* __restrict__ wv,
    unsigned short* __restrict__ xb, unsigned short* __restrict__ wb) {
  int i = (blockIdx.x * 256 + threadIdx.x) * 4;
  float4 v;
  unsigned short* dp;
  if (i < 4194304) {
    v = *(const float4*)(x + i);
    dp = xb + i;
  } else {
    int j = i - 4194304;
    int seg = j >> 20, r = j & 1048575;
    const float* w = (seg == 0) ? wq : (seg == 1) ? wk : wv;
    v = *(const float4*)(w + r);
    dp = wb + j;
  }
  ushort4 o;
  o.x = f2bf(v.x); o.y = f2bf(v.y); o.z = f2bf(v.z); o.w = f2bf(v.w);
  *(ushort4*)dp = o;
}

// ---------------- kernel 2: QKV projection GEMM ----------------
// 64x128 (MxN) tiles -> grid 24x64 = 1536 blocks = 6 blocks/CU. LDS
// 24KB/block; XOR-swizzled LDS, all-b128, GLL staging. Epilogue: Q
// pre-scaled; V transposed [bh][d][t]. (unchanged, proven)
__global__ __launch_bounds__(256) void qkv_gemm(
    const unsigned short* __restrict__ A, const unsigned short* __restrict__ Bm,
    unsigned short* __restrict__ qkv) {
  __shared__ __attribute__((aligned(16))) unsigned short Alds[64 * 64];
  __shared__ __attribute__((aligned(16))) unsigned short Blds[128 * 64];
  const int tid = threadIdx.x;
  const int lane = tid & 63, wave = tid >> 6;
  const int wm = wave >> 1, wn = wave & 1;  // 2x2 waves over 64x128
  const int m0 = blockIdx.y * 64, n0 = blockIdx.x * 128;

  f32x4 acc[2][4] = {};

  const int srA = wave * 16 + (lane >> 3);  // A staging row (2 issues x 8)
  const int srB = wave * 32 + (lane >> 3);  // B staging row (4 issues x 8)
  const int scol = (((lane & 7) ^ ((lane >> 3) & 7))) * 8;
  const unsigned short* ag = A  + (size_t)(m0 + srA) * DIN + scol;
  const unsigned short* bg = Bm + (size_t)(n0 + srB) * DIN + scol;
  unsigned short* al = &Alds[wave * 16 * 64];
  unsigned short* bl = &Blds[wave * 32 * 64];

  const int l16 = lane & 15, quad = lane >> 4;
  const int sw = l16 & 7;

  for (int k0 = 0; k0 < DIN; k0 += 64) {
    __syncthreads();
#pragma unroll
    for (int i = 0; i < 2; i++)
      GLL(ag + (size_t)i * 8 * DIN + k0, al + i * 512);
#pragma unroll
    for (int i = 0; i < 4; i++)
      GLL(bg + (size_t)i * 8 * DIN + k0, bl + i * 512);
    __syncthreads();
#pragma unroll
    for (int ks = 0; ks < 2; ks++) {
      const int cl = ((ks * 4 + quad) ^ sw) * 8;
      s16x8 af[2], bf[4];
#pragma unroll
      for (int mt = 0; mt < 2; mt++)
        af[mt] = *(const s16x8*)&Alds[(wm * 32 + mt * 16 + l16) * 64 + cl];
#pragma unroll
      for (int nt = 0; nt < 4; nt++)
        bf[nt] = *(const s16x8*)&Blds[(wn * 64 + nt * 16 + l16) * 64 + cl];
#pragma unroll
      for (int mt = 0; mt < 2; mt++)
#pragma unroll
        for (int nt = 0; nt < 4; nt++)
          acc[mt][nt] = MFMA32(af[mt], bf[nt], acc[mt][nt]);
    }
  }

#pragma unroll
  for (int mt = 0; mt < 2; mt++) {
    int mbase = m0 + wm * 32 + mt * 16 + (quad << 2);
    int b = mbase >> 11, t = mbase & 2047;
#pragma unroll
    for (int nt = 0; nt < 4; nt++) {
      int n = n0 + wn * 64 + nt * 16 + l16;
      int sel = n >> 10, h = (n >> 6) & 15, d = n & 63;
      int bh = b * NH + h;
      if (sel == 2) {
        ushort4 pk;
        pk.x = f2bf(acc[mt][nt][0]); pk.y = f2bf(acc[mt][nt][1]);
        pk.z = f2bf(acc[mt][nt][2]); pk.w = f2bf(acc[mt][nt][3]);
        *(ushort4*)&qkv[8388608 + (size_t)(bh * HD + d) * T_ + t] = pk;
      } else {
        float qs = (sel == 0) ? SCALE_LOG2 : 1.f;  // fold softmax scale into Q
#pragma unroll
        for (int r = 0; r < 4; r++)
          qkv[(size_t)sel * 4194304 + (size_t)(bh * T_ + t + r) * HD + d] =
              f2bf(acc[mt][nt][r] * qs);
      }
    }
  }
}

// ---------------- kernel 3: causal flash attention (v4) ----------------
// v3 post-mortem: paired tiles fixed the imbalance (occ 11.9->17.4) but
// attn stuck at 49.6us with no pipe saturated -> per-iter structural stall.
// Cause: prefetch loads issued BETWEEN ds_writes and the 2nd __syncthreads;
// barrier lowering emits s_waitcnt vmcnt(0) -> every iter serially eats the
// full L2 load latency right after issue (prefetch overlaps nothing).
// v4 = v2's proven single-barrier GLL loop structure + v3's proven 4-wave
// body + pairing: K/V double-buffered in LDS (40KB), staged by
// global_load_lds with pre-swizzled per-lane source columns; GLLs for tile
// it+1 issued into buf[cur^1] right AFTER the single barrier, so they fly
// during the whole compute phase and are retired by the NEXT iteration's
// implicit vmcnt(0). The barrier's implicit lgkmcnt(0) also retires last
// iter's reads of buf[cur^1] before its overwrite (v2's proven-safe
// argument). One barrier per k-tile, no staging regs, no ds_writes.
__device__ __forceinline__ void tile_step(
    const unsigned short* Klds, const unsigned short* Vt,
    unsigned short* Plds, const s16x8 qf0, const s16x8 qf1,
    f32x4 o[4], f32x4& lacc,
    const int l16, const int quad, const int swl, const int wave,
    const bool diag) {
  // S^T = K @ Q^T : m = key (64), n = 16 q of this wave
  f32x4 s[4] = {};
#pragma unroll
  for (int kk = 0; kk < 2; kk++) {
    const int cl = ((kk * 4 + quad) ^ swl) * 8;
    const s16x8 q = kk ? qf1 : qf0;
#pragma unroll
    for (int mt = 0; mt < 4; mt++) {
      s16x8 kf = *(const s16x8*)&Klds[(mt * 16 + l16) * 64 + cl];
      s[mt] = MFMA32(kf, q, s[mt]);
    }
  }

  // P = exp2(S) -> LDS bf16. logical chunk 2mt+(quad>>1), phys ^swl.
  uint32_t* prow = (uint32_t*)&Plds[(wave * 16 + l16) * 64];
  if (!diag) {
#pragma unroll
    for (int mt = 0; mt < 4; mt++) {
      float p0 = exp2f(s[mt][0]);
      float p1 = exp2f(s[mt][1]);
      float p2 = exp2f(s[mt][2]);
      float p3 = exp2f(s[mt][3]);
      *(uint2*)&prow[(((2 * mt + (quad >> 1)) ^ swl) << 2) + (quad & 1) * 2] =
          make_uint2(pk_bf16(p0, p1), pk_bf16(p2, p3));
    }
  } else {  // causal mask (key <= q) on the diagonal tile
    const int lim = wave * 16 + l16;
#pragma unroll
    for (int mt = 0; mt < 4; mt++) {
      const int kb = mt * 16 + quad * 4;
      float p0 = (kb + 0 <= lim) ? exp2f(s[mt][0]) : 0.f;
      float p1 = (kb + 1 <= lim) ? exp2f(s[mt][1]) : 0.f;
      float p2 = (kb + 2 <= lim) ? exp2f(s[mt][2]) : 0.f;
      float p3 = (kb + 3 <= lim) ? exp2f(s[mt][3]) : 0.f;
      *(uint2*)&prow[(((2 * mt + (quad >> 1)) ^ swl) << 2) + (quad & 1) * 2] =
          make_uint2(pk_bf16(p0, p1), pk_bf16(p2, p3));
    }
  }

  // O += P @ V ; l += P @ 1 (same-wave P rows: compiler inserts lgkmcnt)
  const s16x8 onesf = {0x3F80, 0x3F80, 0x3F80, 0x3F80,
                       0x3F80, 0x3F80, 0x3F80, 0x3F80};
  const unsigned short* prd = &Plds[(wave * 16 + l16) * 64];
#pragma unroll
  for (int kk = 0; kk < 2; kk++) {
    const int cl = ((kk * 4 + quad) ^ swl) * 8;
    s16x8 pf = *(const s16x8*)&prd[cl];
    lacc = MFMA32(pf, onesf, lacc);
#pragma unroll
    for (int dt = 0; dt < 4; dt++) {
      s16x8 vf = *(const s16x8*)&Vt[(dt * 16 + l16) * 64 + cl];
      o[dt] = MFMA32(pf, vf, o[dt]);
    }
  }
}

__global__ __launch_bounds__(256) void attn_kernel(
    const unsigned short* __restrict__ qkv, float* __restrict__ out) {
  __shared__ __attribute__((aligned(16))) unsigned short Kl[2][64 * 64];
  __shared__ __attribute__((aligned(16))) unsigned short Vl[2][64 * 64];
  __shared__ __attribute__((aligned(16))) unsigned short Plds[64 * 64];

  const int tid = threadIdx.x;
  const int lane = tid & 63, wave = tid >> 6;
  const int l16 = lane & 15, quad = lane >> 4;
  const int swl = l16 & 7;
  const int bh = blockIdx.x;
  const int qb = blockIdx.y;        // short q-tile: qb+1 k-tiles (0..15)
  const int qa = 31 - qb;           // long q-tile: qa+1 k-tiles (16..31)
  const size_t bh_off = (size_t)bh * (T_ * HD);
  const unsigned short* Q  = qkv + bh_off;            // [t][d], pre-scaled
  const unsigned short* Kb = qkv + 4194304 + bh_off;  // [t][d]
  const unsigned short* Vb = qkv + 8388608 + bh_off;  // [d][t]

  // Q fragments for both q-tiles (16 q-rows per wave each)
  s16x8 qfa0, qfa1, qfb0, qfb1;
  {
    const unsigned short* qp =
        Q + (size_t)(qa * 64 + wave * 16 + l16) * HD + quad * 8;
    qfa0 = *(const s16x8*)(qp);
    qfa1 = *(const s16x8*)(qp + 32);
    const unsigned short* qq =
        Q + (size_t)(qb * 64 + wave * 16 + l16) * HD + quad * 8;
    qfb0 = *(const s16x8*)(qq);
    qfb1 = *(const s16x8*)(qq + 32);
  }

  // GLL staging: wave w covers 16 rows (2 GLL issues x 8 rows) of K
  // (t-rows) and V (d-rows). Per GLL i: row = w*16+i*8+(lane>>3), LDS phys
  // chunk lane&7; source col chunk pre-swizzled = (lane&7)^(lane>>3)
  // (row&7 == lane>>3). LDS dest linear; readers apply the same XOR.
  const int r8 = lane >> 3;
  const int xc = ((lane & 7) ^ r8) * 8;
  const unsigned short* kg = Kb + (size_t)(wave * 16 + r8) * HD + xc;
  const unsigned short* vg = Vb + (size_t)(wave * 16 + r8) * T_ + xc;
  const int sbase = wave * 16 * 64;

  f32x4 oa[4] = {}, ob[4] = {};
  f32x4 la = {}, lb = {};

  // prologue: tile 0 -> buffer 0
#pragma unroll
  for (int i = 0; i < 2; i++) {
    GLL(kg + (size_t)i * 8 * HD, &Kl[0][sbase + i * 8 * 64]);
    GLL(vg + (size_t)i * 8 * T_, &Vl[0][sbase + i * 8 * 64]);
  }

  // flat sequence of 33 k-tiles: kt = 0..qa (phase a), then 0..qb (phase b)
  int cur = 0;
  for (int it = 0; it < 33; it++) {
    __syncthreads();  // implicit vmcnt(0)+lgkmcnt(0): buf[cur] ready, and
                      // last iter's reads of buf[cur^1] retired
    if (it < 32) {    // issue next tile's GLLs; they fly during compute
      const int nk = (it < qa) ? it + 1 : it - qa;
      const unsigned short* kp = kg + (size_t)nk * 64 * HD;
      const unsigned short* vp = vg + nk * 64;
      unsigned short* kd = &Kl[cur ^ 1][sbase];
      unsigned short* vd = &Vl[cur ^ 1][sbase];
#pragma unroll
      for (int i = 0; i < 2; i++) {
        GLL(kp + (size_t)i * 8 * HD, kd + i * 8 * 64);
        GLL(vp + (size_t)i * 8 * T_, vd + i * 8 * 64);
      }
    }

    if (it <= qa)
      tile_step(Kl[cur], Vl[cur], Plds, qfa0, qfa1, oa, la, l16, quad, swl,
                wave, it == qa);
    else
      tile_step(Kl[cur], Vl[cur], Plds, qfb0, qfb1, ob, lb, l16, quad, swl,
                wave, it == 32);
    cur ^= 1;
  }

  // normalize + store both q-tiles: lacc rows (quad*4+r) match O rows
#pragma unroll
  for (int half = 0; half < 2; half++) {
    const f32x4* o = half ? ob : oa;
    const f32x4 lacc = half ? lb : la;
    const int q0 = (half ? qb : qa) * 64;
    f32x4 inv;
#pragma unroll
    for (int r = 0; r < 4; r++) inv[r] = 1.f / lacc[r];
#pragma unroll
    for (int dt = 0; dt < 4; dt++) {
      float4 v = make_float4(o[dt][0] * inv[0], o[dt][1] * inv[1],
                             o[dt][2] * inv[2], o[dt][3] * inv[3]);
      *(float4*)(out + (size_t)bh * (HD * T_) + (size_t)(dt * 16 + l16) * T_ +
                 q0 + wave * 16 + quad * 4) = v;
    }
  }
}

extern "C" void kernel_launch(void* const* d_in, const int* in_sizes, int n_in,
                              void* d_out, int out_size, void* d_ws, size_t ws_size,
                              hipStream_t stream) {
  const float* x  = (const float*)d_in[0];
  const float* wq = (const float*)d_in[1];
  const float* wk = (const float*)d_in[2];
  const float* wv = (const float*)d_in[3];
  float* out = (float*)d_out;

  unsigned short* xb  = (unsigned short*)d_ws;       // 4194304 bf16
  unsigned short* wb  = xb + 4194304;                // 3145728 bf16 [Wq;Wk;Wv]
  unsigned short* qkv = wb + 3145728;                // 3 * 4194304 bf16

  cvt_kernel<<<7168, 256, 0, stream>>>(x, wq, wk, wv, xb, wb);
  dim3 g1(24, 64);  // N/128 x M/64 -> 1536 blocks, 6/CU
  qkv_gemm<<<g1, 256, 0, stream>>>(xb, wb, qkv);
  dim3 g2(32, 16);  // bh x pair -> 512 blocks, each exactly 33 k-tile iters
  attn_kernel<<<g2, 256, 0, stream>>>(qkv, out);
}

// Round 5
// 150.430 us; speedup vs baseline: 1.0466x; 1.0466x over previous
//
#include <hip/hip_runtime.h>
#include <hip/hip_bf16.h>
#include <stdint.h>

typedef __attribute__((ext_vector_type(8))) short s16x8;
typedef __attribute__((ext_vector_type(4))) float f32x4;

#define T_   2048
#define NH   16
#define HD   64
#define DIN  1024
#define SCALE_LOG2 0.18033688011112042f  // (1/8)*log2(e)

#define MFMA32(a, b, c) __builtin_amdgcn_mfma_f32_16x16x32_bf16(a, b, c, 0, 0, 0)

// RTNE fp32 -> bf16
__device__ __forceinline__ unsigned short f2bf(float f) {
  union { float f; uint32_t u; } c; c.f = f;
  uint32_t u = c.u;
  return (unsigned short)((u + 0x7FFFu + ((u >> 16) & 1u)) >> 16);
}

__device__ __forceinline__ uint32_t pk_bf16(float a, float b) {
  __hip_bfloat162 h = __float22bfloat162_rn(make_float2(a, b));
  return *reinterpret_cast<uint32_t*>(&h);
}

// async global->LDS, 16B per lane; dest = wave-uniform base + lane*16
#define GLL(gp, lp) __builtin_amdgcn_global_load_lds( \
    (__attribute__((address_space(1))) void*)(gp),    \
    (__attribute__((address_space(3))) void*)(lp), 16, 0, 0)

// ---------------- kernel 1: fp32 -> bf16 conversion ----------------
__global__ __launch_bounds__(256) void cvt_kernel(
    const float* __restrict__ x,  const float* __restrict__ wq,
    const float* __restrict__ wk, const float* __restrict__ wv,
    unsigned short* __restrict__ xb, unsigned short* __restrict__ wb) {
  int i = (blockIdx.x * 256 + threadIdx.x) * 4;
  float4 v;
  unsigned short* dp;
  if (i < 4194304) {
    v = *(const float4*)(x + i);
    dp = xb + i;
  } else {
    int j = i - 4194304;
    int seg = j >> 20, r = j & 1048575;
    const float* w = (seg == 0) ? wq : (seg == 1) ? wk : wv;
    v = *(const float4*)(w + r);
    dp = wb + j;
  }
  ushort4 o;
  o.x = f2bf(v.x); o.y = f2bf(v.y); o.z = f2bf(v.z); o.w = f2bf(v.w);
  *(ushort4*)dp = o;
}

// ---------------- kernel 2: QKV projection GEMM ----------------
// 64x128 (MxN) tiles -> grid 24x64 = 1536 blocks = 6 blocks/CU. LDS
// 24KB/block; XOR-swizzled LDS, all-b128, GLL staging. Epilogue: Q
// pre-scaled; V transposed [bh][d][t]. (unchanged, proven)
__global__ __launch_bounds__(256) void qkv_gemm(
    const unsigned short* __restrict__ A, const unsigned short* __restrict__ Bm,
    unsigned short* __restrict__ qkv) {
  __shared__ __attribute__((aligned(16))) unsigned short Alds[64 * 64];
  __shared__ __attribute__((aligned(16))) unsigned short Blds[128 * 64];
  const int tid = threadIdx.x;
  const int lane = tid & 63, wave = tid >> 6;
  const int wm = wave >> 1, wn = wave & 1;  // 2x2 waves over 64x128
  const int m0 = blockIdx.y * 64, n0 = blockIdx.x * 128;

  f32x4 acc[2][4] = {};

  const int srA = wave * 16 + (lane >> 3);  // A staging row (2 issues x 8)
  const int srB = wave * 32 + (lane >> 3);  // B staging row (4 issues x 8)
  const int scol = (((lane & 7) ^ ((lane >> 3) & 7))) * 8;
  const unsigned short* ag = A  + (size_t)(m0 + srA) * DIN + scol;
  const unsigned short* bg = Bm + (size_t)(n0 + srB) * DIN + scol;
  unsigned short* al = &Alds[wave * 16 * 64];
  unsigned short* bl = &Blds[wave * 32 * 64];

  const int l16 = lane & 15, quad = lane >> 4;
  const int sw = l16 & 7;

  for (int k0 = 0; k0 < DIN; k0 += 64) {
    __syncthreads();
#pragma unroll
    for (int i = 0; i < 2; i++)
      GLL(ag + (size_t)i * 8 * DIN + k0, al + i * 512);
#pragma unroll
    for (int i = 0; i < 4; i++)
      GLL(bg + (size_t)i * 8 * DIN + k0, bl + i * 512);
    __syncthreads();
#pragma unroll
    for (int ks = 0; ks < 2; ks++) {
      const int cl = ((ks * 4 + quad) ^ sw) * 8;
      s16x8 af[2], bf[4];
#pragma unroll
      for (int mt = 0; mt < 2; mt++)
        af[mt] = *(const s16x8*)&Alds[(wm * 32 + mt * 16 + l16) * 64 + cl];
#pragma unroll
      for (int nt = 0; nt < 4; nt++)
        bf[nt] = *(const s16x8*)&Blds[(wn * 64 + nt * 16 + l16) * 64 + cl];
#pragma unroll
      for (int mt = 0; mt < 2; mt++)
#pragma unroll
        for (int nt = 0; nt < 4; nt++)
          acc[mt][nt] = MFMA32(af[mt], bf[nt], acc[mt][nt]);
    }
  }

#pragma unroll
  for (int mt = 0; mt < 2; mt++) {
    int mbase = m0 + wm * 32 + mt * 16 + (quad << 2);
    int b = mbase >> 11, t = mbase & 2047;
#pragma unroll
    for (int nt = 0; nt < 4; nt++) {
      int n = n0 + wn * 64 + nt * 16 + l16;
      int sel = n >> 10, h = (n >> 6) & 15, d = n & 63;
      int bh = b * NH + h;
      if (sel == 2) {
        ushort4 pk;
        pk.x = f2bf(acc[mt][nt][0]); pk.y = f2bf(acc[mt][nt][1]);
        pk.z = f2bf(acc[mt][nt][2]); pk.w = f2bf(acc[mt][nt][3]);
        *(ushort4*)&qkv[8388608 + (size_t)(bh * HD + d) * T_ + t] = pk;
      } else {
        float qs = (sel == 0) ? SCALE_LOG2 : 1.f;  // fold softmax scale into Q
#pragma unroll
        for (int r = 0; r < 4; r++)
          qkv[(size_t)sel * 4194304 + (size_t)(bh * T_ + t + r) * HD + d] =
              f2bf(acc[mt][nt][r] * qs);
      }
    }
  }
}

// ---------------- kernel 3: causal flash attention (v5: split-k) ----------
// v3/v4 post-mortem: staging structure irrelevant (49.6 vs 51.2); CU
// throughput scales with resident waves (16w/CU -> 1305 cyc/tile, 8w/CU ->
// 1855). Latency-chain-bound: the lever is occupancy x balance together.
// v5: max-free softmax => (O,l) partials are additive => split-k. Per bh:
//   qt<16  -> 1 block, k-tiles 0..qt, writes out directly.
//   qt>=16 -> 2 blocks: lo (k 0..15) and hi (k 16..qt), write f32 partials.
// Grid 32x48=1536 blocks, 24KB LDS -> 6 blocks/CU = 24 waves/CU. Max job
// 16 tiles; blockIdx.y permuted so 16-tile jobs dispatch first and short
// jobs backfill (balance via scheduler backfill, not static pairing).
// Inner body = proven v3 tile_step. Small combine kernel normalizes qt>=16.
__device__ __forceinline__ void tile_step(
    const unsigned short* Klds, const unsigned short* Vt,
    unsigned short* Plds, const s16x8 qf0, const s16x8 qf1,
    f32x4 o[4], f32x4& lacc,
    const int l16, const int quad, const int swl, const int wave,
    const bool diag) {
  // S^T = K @ Q^T : m = key (64), n = 16 q of this wave
  f32x4 s[4] = {};
#pragma unroll
  for (int kk = 0; kk < 2; kk++) {
    const int cl = ((kk * 4 + quad) ^ swl) * 8;
    const s16x8 q = kk ? qf1 : qf0;
#pragma unroll
    for (int mt = 0; mt < 4; mt++) {
      s16x8 kf = *(const s16x8*)&Klds[(mt * 16 + l16) * 64 + cl];
      s[mt] = MFMA32(kf, q, s[mt]);
    }
  }

  // P = exp2(S) -> LDS bf16. logical chunk 2mt+(quad>>1), phys ^swl.
  uint32_t* prow = (uint32_t*)&Plds[(wave * 16 + l16) * 64];
  if (!diag) {
#pragma unroll
    for (int mt = 0; mt < 4; mt++) {
      float p0 = exp2f(s[mt][0]);
      float p1 = exp2f(s[mt][1]);
      float p2 = exp2f(s[mt][2]);
      float p3 = exp2f(s[mt][3]);
      *(uint2*)&prow[(((2 * mt + (quad >> 1)) ^ swl) << 2) + (quad & 1) * 2] =
          make_uint2(pk_bf16(p0, p1), pk_bf16(p2, p3));
    }
  } else {  // causal mask (key <= q) on the diagonal tile
    const int lim = wave * 16 + l16;
#pragma unroll
    for (int mt = 0; mt < 4; mt++) {
      const int kb = mt * 16 + quad * 4;
      float p0 = (kb + 0 <= lim) ? exp2f(s[mt][0]) : 0.f;
      float p1 = (kb + 1 <= lim) ? exp2f(s[mt][1]) : 0.f;
      float p2 = (kb + 2 <= lim) ? exp2f(s[mt][2]) : 0.f;
      float p3 = (kb + 3 <= lim) ? exp2f(s[mt][3]) : 0.f;
      *(uint2*)&prow[(((2 * mt + (quad >> 1)) ^ swl) << 2) + (quad & 1) * 2] =
          make_uint2(pk_bf16(p0, p1), pk_bf16(p2, p3));
    }
  }

  // O += P @ V ; l += P @ 1 (same-wave P rows: compiler inserts lgkmcnt)
  const s16x8 onesf = {0x3F80, 0x3F80, 0x3F80, 0x3F80,
                       0x3F80, 0x3F80, 0x3F80, 0x3F80};
  const unsigned short* prd = &Plds[(wave * 16 + l16) * 64];
#pragma unroll
  for (int kk = 0; kk < 2; kk++) {
    const int cl = ((kk * 4 + quad) ^ swl) * 8;
    s16x8 pf = *(const s16x8*)&prd[cl];
    lacc = MFMA32(pf, onesf, lacc);
#pragma unroll
    for (int dt = 0; dt < 4; dt++) {
      s16x8 vf = *(const s16x8*)&Vt[(dt * 16 + l16) * 64 + cl];
      o[dt] = MFMA32(pf, vf, o[dt]);
    }
  }
}

__global__ __launch_bounds__(256) void attn_kernel(
    const unsigned short* __restrict__ qkv, float* __restrict__ out,
    float* __restrict__ op, float* __restrict__ lp) {
  __shared__ __attribute__((aligned(16))) unsigned short Klds[64 * 64];
  __shared__ __attribute__((aligned(16))) unsigned short Vt[64 * 64];
  __shared__ __attribute__((aligned(16))) unsigned short Plds[64 * 64];

  const int tid = threadIdx.x;
  const int lane = tid & 63, wave = tid >> 6;
  const int l16 = lane & 15, quad = lane >> 4;
  const int swl = l16 & 7;
  const int bh = blockIdx.x;

  // job permutation: y -> j so that all 18 len-16 jobs have smallest y
  // (dispatch first); then pairs of len 15,15,14,14,...,1,1.
  const int y = blockIdx.y;
  int j;
  if (y < 18) {
    j = (y == 0) ? 15 : ((y == 17) ? 47 : 15 + y);
  } else {
    const int z = y - 18, L = 15 - (z >> 1);
    j = (z & 1) ? (L - 1) : (L + 31);
  }
  // decode job: qt<16 full; qt>=16 split into lo (0..15) / hi (16..qt)
  int qt, kt0, kt1, hi;
  bool split;
  if (j < 16)      { qt = j;      kt0 = 0;  kt1 = j;  split = false; hi = 0; }
  else if (j < 32) { qt = j;      kt0 = 0;  kt1 = 15; split = true;  hi = 0; }
  else             { qt = j - 16; kt0 = 16; kt1 = qt; split = true;  hi = 1; }

  const size_t bh_off = (size_t)bh * (T_ * HD);
  const unsigned short* Q  = qkv + bh_off;            // [t][d], pre-scaled
  const unsigned short* Kb = qkv + 4194304 + bh_off;  // [t][d]
  const unsigned short* Vb = qkv + 8388608 + bh_off;  // [d][t]

  // Q fragments: 16 q-rows per wave
  s16x8 qf0, qf1;
  {
    const unsigned short* qp =
        Q + (size_t)(qt * 64 + wave * 16 + l16) * HD + quad * 8;
    qf0 = *(const s16x8*)(qp);
    qf1 = *(const s16x8*)(qp + 32);
  }

  // K/V staging: reg prefetch, XOR-swizzled LDS write (proven)
  const int sr = tid >> 3;                 // staging row 0..31
  const int sc = (tid & 7) * 8;            // linear global chunk
  const int swc = (((tid & 7) ^ (sr & 7))) * 8;  // swizzled LDS chunk

  s16x8 kr0 = *(const s16x8*)&Kb[(size_t)(kt0 * 64 + sr) * HD + sc];
  s16x8 kr1 = *(const s16x8*)&Kb[(size_t)(kt0 * 64 + sr + 32) * HD + sc];
  s16x8 vr0 = *(const s16x8*)&Vb[(size_t)sr * T_ + kt0 * 64 + sc];
  s16x8 vr1 = *(const s16x8*)&Vb[(size_t)(sr + 32) * T_ + kt0 * 64 + sc];

  f32x4 o[4] = {};
  f32x4 lacc = {};

  for (int kt = kt0; kt <= kt1; kt++) {
    __syncthreads();
    *(s16x8*)&Klds[sr * 64 + swc] = kr0;
    *(s16x8*)&Klds[(sr + 32) * 64 + swc] = kr1;
    *(s16x8*)&Vt[sr * 64 + swc] = vr0;
    *(s16x8*)&Vt[(sr + 32) * 64 + swc] = vr1;
    if (kt < kt1) {  // prefetch next k-tile
      const unsigned short* kp = Kb + (size_t)(kt + 1) * 64 * HD;
      const unsigned short* vp = Vb + (kt + 1) * 64;
      kr0 = *(const s16x8*)&kp[(size_t)sr * HD + sc];
      kr1 = *(const s16x8*)&kp[(size_t)(sr + 32) * HD + sc];
      vr0 = *(const s16x8*)&vp[(size_t)sr * T_ + sc];
      vr1 = *(const s16x8*)&vp[(size_t)(sr + 32) * T_ + sc];
    }
    __syncthreads();

    tile_step(Klds, Vt, Plds, qf0, qf1, o, lacc, l16, quad, swl, wave,
              kt == qt);
  }

  if (!split) {
    // normalize + store directly: lacc rows (quad*4+r) match O rows
    f32x4 inv;
#pragma unroll
    for (int r = 0; r < 4; r++) inv[r] = 1.f / lacc[r];
#pragma unroll
    for (int dt = 0; dt < 4; dt++) {
      float4 v = make_float4(o[dt][0] * inv[0], o[dt][1] * inv[1],
                             o[dt][2] * inv[2], o[dt][3] * inv[3]);
      *(float4*)(out + (size_t)bh * (HD * T_) + (size_t)(dt * 16 + l16) * T_ +
                 qt * 64 + wave * 16 + quad * 4) = v;
    }
  } else {
    // write f32 partials: O_p [slot][d:64][q:64], l_p [slot][q:64]
    const int slot = ((bh * 16 + (qt - 16)) << 1) + hi;
    float* Op = op + (size_t)slot * 4096;
    float* Lp = lp + (size_t)slot * 64;
#pragma unroll
    for (int dt = 0; dt < 4; dt++) {
      float4 v = make_float4(o[dt][0], o[dt][1], o[dt][2], o[dt][3]);
      *(float4*)(Op + (dt * 16 + l16) * 64 + wave * 16 + quad * 4) = v;
    }
    if (l16 == 0) {
#pragma unroll
      for (int r = 0; r < 4; r++) Lp[wave * 16 + quad * 4 + r] = lacc[r];
    }
  }
}

// combine: out[bh][d][qt*64+q] = (Olo+Ohi)[d][q] / (Llo+Lhi)[q], qt>=16
__global__ __launch_bounds__(256) void combine_kernel(
    const float* __restrict__ op, const float* __restrict__ lp,
    float* __restrict__ out) {
  const int bh = blockIdx.x, j2 = blockIdx.y;  // j2 = qt-16
  const int slot = (bh * 16 + j2) << 1;
  const float* Olo = op + (size_t)slot * 4096;
  const float* Ohi = Olo + 4096;
  const float* Llo = lp + (size_t)slot * 64;
  const int t = threadIdx.x;
  const int q = t & 63, d0 = (t >> 6) * 16;
  const float inv = 1.f / (Llo[q] + Llo[64 + q]);
  float* ob = out + (size_t)bh * (HD * T_) + (size_t)(j2 + 16) * 64 + q;
#pragma unroll
  for (int dd = 0; dd < 16; dd++) {
    const int d = d0 + dd;
    ob[(size_t)d * T_] = (Olo[d * 64 + q] + Ohi[d * 64 + q]) * inv;
  }
}

extern "C" void kernel_launch(void* const* d_in, const int* in_sizes, int n_in,
                              void* d_out, int out_size, void* d_ws, size_t ws_size,
                              hipStream_t stream) {
  const float* x  = (const float*)d_in[0];
  const float* wq = (const float*)d_in[1];
  const float* wk = (const float*)d_in[2];
  const float* wv = (const float*)d_in[3];
  float* out = (float*)d_out;

  unsigned short* xb  = (unsigned short*)d_ws;       // 4194304 bf16
  unsigned short* wb  = xb + 4194304;                // 3145728 bf16 [Wq;Wk;Wv]
  unsigned short* qkv = wb + 3145728;                // 3 * 4194304 bf16
  float* op = (float*)(qkv + 12582912);              // 32*16*2*4096 f32
  float* lp = op + 4194304;                          // 32*16*2*64 f32

  cvt_kernel<<<7168, 256, 0, stream>>>(x, wq, wk, wv, xb, wb);
  dim3 g1(24, 64);  // N/128 x M/64 -> 1536 blocks, 6/CU
  qkv_gemm<<<g1, 256, 0, stream>>>(xb, wb, qkv);
  dim3 g2(32, 48);  // bh x permuted job -> 1536 blocks, 6/CU, max 16 tiles
  attn_kernel<<<g2, 256, 0, stream>>>(qkv, out, op, lp);
  dim3 g3(32, 16);  // bh x (qt-16): normalize split q-tiles
  combine_kernel<<<g3, 256, 0, stream>>>(op, lp, out);
}